// Round 9
// baseline (568.669 us; speedup 1.0000x reference)
//
#include <hip/hip_runtime.h>
#include <math.h>

// ConvGRU scan, bf16 MFMA 16x16x32, 128 blocks x 512 threads (8 waves).
// r5 structure + B-read sharing in P1 AND P2: wave (gate, stile) reads the
// stile's 9 B-frags once and computes both 16-co halves (4 MFMA chains).
// Reads/step/wave: 36 (r5: 54). No launch_bounds min-occupancy (grid=128
// means 1 block/CU regardless) so the allocator can avoid scratch spills.

#define TT 64
#define NB 128
#define CC 32
#define AA 8
#define SS 49
#define HH 1568
#define KK 288      // 9 taps * 32 channels, all six convs
#define NKB 9
#define NPOS 81
#define NTHR 512

typedef short bf16x8 __attribute__((ext_vector_type(8)));
typedef short bf16x4 __attribute__((ext_vector_type(4)));
typedef float f32x4 __attribute__((ext_vector_type(4)));

struct __align__(16) SMEM {
  union {
    short staging[CC * KK];             // 9216 shorts weight scratch
    struct {
      short stacked[NPOS * CC];         // prev (or prev*r), swizzled
      short img_u[NPOS * CC];           // u1 / o1 relu output
      short img_r[NPOS * CC];           // r1 relu output
    } im;
  } u;
  short wsum[3 * 9 * CC * AA];          // bf16 class-summed inp weights [g][cls][co][ci]
  short cArr[3 * 9 * CC];               // per-step inp term + conv1 bias [g][cls][co]
  float sH[HH];
  float sU[HH];
  float sO[HH];
  float bias[6 * CC];                   // bu1,bu2,br1,br2,bo1,bo2
};

__device__ __forceinline__ short f2bf(float v) {
  union { float f; unsigned u; } a; a.f = v;
  unsigned r = a.u + 0x7FFFu + ((a.u >> 16) & 1u);
  return (short)(r >> 16);
}
__device__ __forceinline__ float b2f(short h) {
  union { unsigned u; float f; } a; a.u = ((unsigned)(unsigned short)h) << 16;
  return a.f;
}
__device__ __forceinline__ float sigm(float v) { return 1.f / (1.f + __expf(-v)); }
__device__ __forceinline__ float tanhfast(float v) { return 2.f / (1.f + __expf(-2.f * v)) - 1.f; }

// image addr swizzle: 32 shorts (64B) per position. XOR short-index bits 3..4
// with (p>>1)&3 -> 8 consecutive positions hit 8 distinct 16B bank groups.
__device__ __forceinline__ int swz(int p, int ci) {
  return ((p << 5) + ci) ^ (((p >> 1) & 3) << 3);
}
__device__ __forceinline__ int clsOf(int s) {
  int y = s / 7, x = s - y * 7;
  return (y == 0 ? 0 : (y == 6 ? 6 : 3)) + (x == 0 ? 0 : (x == 6 ? 2 : 1));
}

#define MFMA(A, B, C) __builtin_amdgcn_mfma_f32_16x16x32_bf16((A), (B), (C), 0, 0, 0)

// single-mtile conv (P3/P4), dual accumulator chains
__device__ __forceinline__ f32x4 conv288(const short* img, const bf16x8 (&fA)[NKB],
                                         const int (&ad)[NKB])
{
  f32x4 a0 = {0.f, 0.f, 0.f, 0.f}, a1 = {0.f, 0.f, 0.f, 0.f};
#pragma unroll
  for (int b = 0; b < NKB; b += 2) {
    a0 = MFMA(fA[b], *(const bf16x8*)(img + ad[b]), a0);
    if (b + 1 < NKB)
      a1 = MFMA(fA[b + 1], *(const bf16x8*)(img + ad[b + 1]), a1);
  }
  return a0 + a1;
}

// both-mtile conv (P1/P2): one B-read feeds both co-halves (4 chains)
__device__ __forceinline__ void conv288both(const short* img, const bf16x8 (&fA)[2][NKB],
                                            const int (&ad)[NKB], f32x4 (&am)[2])
{
  f32x4 a0m0 = {0.f,0.f,0.f,0.f}, a1m0 = {0.f,0.f,0.f,0.f};
  f32x4 a0m1 = {0.f,0.f,0.f,0.f}, a1m1 = {0.f,0.f,0.f,0.f};
#pragma unroll
  for (int b = 0; b < NKB; b += 2) {
    bf16x8 bv = *(const bf16x8*)(img + ad[b]);
    a0m0 = MFMA(fA[0][b], bv, a0m0);
    a0m1 = MFMA(fA[1][b], bv, a0m1);
    if (b + 1 < NKB) {
      bf16x8 bw = *(const bf16x8*)(img + ad[b + 1]);
      a1m0 = MFMA(fA[0][b + 1], bw, a1m0);
      a1m1 = MFMA(fA[1][b + 1], bw, a1m1);
    }
  }
  am[0] = a0m0 + a1m0;
  am[1] = a0m1 + a1m1;
}

__global__ __launch_bounds__(NTHR)
void convgru_mfma(const float* __restrict__ x, const float* __restrict__ hxs,
                  const float* __restrict__ att, const float* __restrict__ masks,
                  const float* __restrict__ pact,
                  const float* __restrict__ Wr1, const float* __restrict__ br1,
                  const float* __restrict__ Wr2, const float* __restrict__ br2,
                  const float* __restrict__ Wu1, const float* __restrict__ bu1,
                  const float* __restrict__ Wu2, const float* __restrict__ bu2,
                  const float* __restrict__ Wo1, const float* __restrict__ bo1,
                  const float* __restrict__ Wo2, const float* __restrict__ bo2,
                  float* __restrict__ out)
{
  __shared__ SMEM sm;
  const int n = blockIdx.x;
  const int tid = threadIdx.x;
  const int w = __builtin_amdgcn_readfirstlane(tid >> 6);
  const int lane = tid & 63;
  const int gate = w >> 2;            // 0=u, 1=r  (P1/P2 role)
  const int mt = w & 1;               // mtile for P3/P4
  const int stG = w & 3;              // P1/P2 stile (both mt)
  const int stO = w >> 1;             // P3/P4 stile
  const int fg = lane >> 4;
  const int col = lane & 15;
  const int co0 = mt * 16 + fg * 4;   // P3/P4 co base

  // ---- bias staging
  if (tid < 6 * CC) {
    const float* bsrc[6] = {bu1, bu2, br1, br2, bo1, bo2};
    sm.bias[tid] = bsrc[tid >> 5][tid & 31];
  }

  // ---- weight transpose staging + per-wave A-frag preload (k = tap*32 + pc)
  bf16x8 fG1[2][NKB], fG2[2][NKB], fO1[NKB], fO2[NKB];
  {
    const float* wsrc[6] = {Wu1, Wr1, Wo1, Wu2, Wr2, Wo2};
#pragma unroll
    for (int cv = 0; cv < 6; ++cv) {
      __syncthreads();
      const float* wp = wsrc[cv];
      const int cin = (cv < 3) ? (AA + CC) : CC;
      const int cofs = (cv < 3) ? AA : 0;
      for (int i = tid; i < CC * KK; i += NTHR) {
        int co = i / KK, k = i - co * KK;
        int tap = k >> 5, pc = k & 31;
        sm.u.staging[(co * KK + k) ^ ((co & 7) << 3)] =
            f2bf(wp[(co * cin + cofs + pc) * 9 + tap]);
      }
      __syncthreads();
      auto loadfr = [&](bf16x8 (&dst)[NKB], int m) {
        const int fco = m * 16 + col;
#pragma unroll
        for (int b = 0; b < NKB; ++b)
          dst[b] = *(const bf16x8*)&sm.u.staging[(fco * KK + b * 32 + fg * 8) ^ ((fco & 7) << 3)];
      };
      if (cv == 0) { if (gate == 0) { loadfr(fG1[0], 0); loadfr(fG1[1], 1); } }
      else if (cv == 1) { if (gate == 1) { loadfr(fG1[0], 0); loadfr(fG1[1], 1); } }
      else if (cv == 2) { loadfr(fO1, mt); }
      else if (cv == 3) { if (gate == 0) { loadfr(fG2[0], 0); loadfr(fG2[1], 1); } }
      else if (cv == 4) { if (gate == 1) { loadfr(fG2[0], 0); loadfr(fG2[1], 1); } }
      else { loadfr(fO2, mt); }
    }
  }
  __syncthreads();

  // ---- zero images (borders stay 0; staging 9216 covers 3*81*32=7776) + Wsum
  for (int i = tid; i < CC * KK; i += NTHR) sm.u.staging[i] = 0;
  {
    const float* w1s[3] = {Wu1, Wr1, Wo1};
    for (int e = tid; e < 3 * 9 * CC * AA; e += NTHR) {
      int g = e / 2304, rem = e - g * 2304;
      int cls = rem >> 8;
      int co = (rem >> 3) & 31, ci = e & 7;
      int yt = cls / 3, xt = cls - yt * 3;
      const float* wp = w1s[g] + (co * (AA + CC) + ci) * 9;
      float s = 0.f;
#pragma unroll
      for (int r = 0; r < 3; ++r) {
        if ((yt == 0 && r == 0) || (yt == 2 && r == 2)) continue;
#pragma unroll
        for (int c = 0; c < 3; ++c) {
          if ((xt == 0 && c == 0) || (xt == 2 && c == 2)) continue;
          s += wp[r * 3 + c];
        }
      }
      sm.wsum[e] = f2bf(s);
    }
  }

  // ---- per-lane spatial precompute (t-invariant, swizzled)
  // P1/P2: stile stG, both mtiles
  int s1v, in1[NKB], pout1[2], clsA1[2]; bool v1;
  {
    int s = stG * 16 + col;
    v1 = (s < SS); int sc = v1 ? s : (SS - 1); s1v = sc;
    int y = sc / 7, xx = sc - y * 7;
    int p0 = y * 9 + xx;
#pragma unroll
    for (int b = 0; b < NKB; ++b)
      in1[b] = swz(p0 + (b / 3) * 9 + (b % 3), fg * 8);
#pragma unroll
    for (int m = 0; m < 2; ++m) {
      pout1[m] = swz(p0 + 10, m * 16 + fg * 4);
      clsA1[m] = ((gate * 9 + clsOf(sc)) << 5) + m * 16 + fg * 4;
    }
  }
  // P3/P4: stile stO, single mtile
  int sOv, pout_swO, clsAO, inO[NKB]; bool vO;
  {
    int s = stO * 16 + col;
    vO = (s < SS); int sc = vO ? s : (SS - 1); sOv = sc;
    int y = sc / 7, xx = sc - y * 7;
    int p0 = y * 9 + xx;
    pout_swO = swz(p0 + 10, co0);
    clsAO = ((2 * 9 + clsOf(sc)) << 5) + co0;
#pragma unroll
    for (int b = 0; b < NKB; ++b)
      inO[b] = swz(p0 + (b / 3) * 9 + (b % 3), fg * 8);
  }

  // ---- epilogue precompute
  int eidx[4], stSw[4]; bool eval[4];
#pragma unroll
  for (int j = 0; j < 4; ++j) {
    int i = tid + j * NTHR;
    eval[j] = (i < HH);
    int ii = eval[j] ? i : 0;
    eidx[j] = ii;
    int co = ii / SS, s = ii - co * SS;
    int y = s / 7, xx = s - y * 7;
    stSw[j] = swz(y * 9 + xx + 10, co);
  }

  float* out_pmu = out;
  float* out_att = out + (size_t)TT * NB * HH;
  float* out_h   = out + (size_t)2 * TT * NB * HH;

  __syncthreads();

  // conv2 biases to registers: both-mt for P2 gate conv, single-mt for o2
  f32x4 biaG2[2], biaO2;
#pragma unroll
  for (int q = 0; q < 4; ++q) {
#pragma unroll
    for (int m = 0; m < 2; ++m)
      biaG2[m][q] = sm.bias[(gate * 2 + 1) * 32 + m * 16 + fg * 4 + q];
    biaO2[q] = sm.bias[5 * 32 + co0 + q];
  }

  // ---- carr weights PRELOADED to registers
  const int e1 = tid + NTHR;
  const bool ok1 = (e1 < 3 * 9 * CC);
  bf16x8 wR0 = *(const bf16x8*)&sm.wsum[tid << 3];
  float bR0 = sm.bias[((tid / 288) << 6) + (tid & 31)];
  bf16x8 wR1 = ok1 ? *(const bf16x8*)&sm.wsum[e1 << 3] : wR0;
  float bR1 = ok1 ? sm.bias[((e1 / 288) << 6) + (e1 & 31)] : 0.f;

  auto carr = [&](const float (&v)[8]) {
    float acc = bR0;
#pragma unroll
    for (int q = 0; q < 8; ++q) acc = fmaf(b2f(wR0[q]), v[q], acc);
    sm.cArr[tid] = f2bf(acc);
    if (ok1) {
      float a2 = bR1;
#pragma unroll
      for (int q = 0; q < 8; ++q) a2 = fmaf(b2f(wR1[q]), v[q], a2);
      sm.cArr[e1] = f2bf(a2);
    }
  };

  // ---- step-0 build
  float xcar[4];
  {
    const float m0 = masks[n];
    const float* x0 = x + (size_t)n * HH;
    const float* h0 = hxs + (size_t)n * HH;
#pragma unroll
    for (int j = 0; j < 4; ++j) if (eval[j]) {
      float xv = x0[eidx[j]];
      float h = h0[eidx[j]] * m0 + xv * (1.f - m0);
      sm.sH[eidx[j]] = h;
      sm.u.im.stacked[stSw[j]] = f2bf(h);
      xcar[j] = xv;
    }
    float v0[8];
    const float* pa0 = pact + (size_t)n * AA;
#pragma unroll
    for (int q = 0; q < 8; ++q) v0[q] = pa0[q] * m0;
    carr(v0);
  }
  __syncthreads();

  for (int t = 0; t < TT; ++t) {
    const bool last = (t == TT - 1);
    const size_t obase = ((size_t)(t * NB) + n) * HH;

    // prefetch: att(t), x(t+1), masks(t+1), pact(t+1) — consumed in P4/P5
    const float* atp = att + obase;
    const int tn = last ? t : (t + 1);
    const float* xnp = x + ((size_t)(tn * NB) + n) * HH;
    float xnv[4], avv[4];
#pragma unroll
    for (int j = 0; j < 4; ++j) { avv[j] = atp[eidx[j]]; xnv[j] = xnp[eidx[j]]; }
    const float m2 = last ? 0.f : masks[(t + 1) * NB + n];
    float vN[8];
    const float* pap = pact + ((size_t)(tn * NB) + n) * AA;
#pragma unroll
    for (int q = 0; q < 8; ++q) vN[q] = pap[q] * m2;

    // P1: gate conv1 at stile stG, both mtiles (one B-read, 4 MFMA chains)
    {
      short* imgOut = gate ? sm.u.im.img_r : sm.u.im.img_u;
      f32x4 am[2];
      conv288both(sm.u.im.stacked, fG1, in1, am);
      if (v1) {
#pragma unroll
        for (int m = 0; m < 2; ++m) {
          bf16x4 c4 = *(const bf16x4*)&sm.cArr[clsA1[m]];
          bf16x4 pk;
#pragma unroll
          for (int q = 0; q < 4; ++q) pk[q] = f2bf(fmaxf(am[m][q] + b2f(c4[q]), 0.f));
          *(bf16x4*)&imgOut[pout1[m]] = pk;
        }
      }
    }
    __syncthreads();

    // P2: gate conv2 at stile stG, both mtiles.
    //     u2 -> sigmoid -> sU ; r2 -> sigmoid*prev -> stacked (in place)
    {
      const short* imgIn = gate ? sm.u.im.img_r : sm.u.im.img_u;
      f32x4 am[2];
      conv288both(imgIn, fG2, in1, am);
      if (v1) {
        if (gate == 0) {
#pragma unroll
          for (int m = 0; m < 2; ++m)
#pragma unroll
            for (int q = 0; q < 4; ++q)
              sm.sU[(m * 16 + fg * 4 + q) * SS + s1v] = sigm(am[m][q] + biaG2[m][q]);
        } else {
#pragma unroll
          for (int m = 0; m < 2; ++m) {
            bf16x4 pk;
#pragma unroll
            for (int q = 0; q < 4; ++q) {
              float rv = sigm(am[m][q] + biaG2[m][q]);
              pk[q] = f2bf(sm.sH[(m * 16 + fg * 4 + q) * SS + s1v] * rv);
            }
            *(bf16x4*)&sm.u.im.stacked[pout1[m]] = pk;
          }
        }
      }
    }
    __syncthreads();

    // P3: o1 on stacked2 (+cArr class term, relu) -> img_u, 8 jobs / 8 waves
    {
      f32x4 a = conv288(sm.u.im.stacked, fO1, inO);
      if (vO) {
        bf16x4 c4 = *(const bf16x4*)&sm.cArr[clsAO];
        bf16x4 pk;
#pragma unroll
        for (int q = 0; q < 4; ++q) pk[q] = f2bf(fmaxf(a[q] + b2f(c4[q]), 0.f));
        *(bf16x4*)&sm.u.im.img_u[pout_swO] = pk;
      }
    }
    __syncthreads();

    // P4: o2 -> tanh -> sO; then cArr(t+1) from registers (last reader was P3)
    {
      f32x4 a = conv288(sm.u.im.img_u, fO2, inO);
      if (vO) {
#pragma unroll
        for (int q = 0; q < 4; ++q)
          sm.sO[(co0 + q) * SS + sOv] = tanhfast(a[q] + biaO2[q]);
      }
      if (!last) carr(vN);
    }
    __syncthreads();

    // P5: epilogue(t) + build(t+1); globals already in registers
    {
#pragma unroll
      for (int j = 0; j < 4; ++j) if (eval[j]) {
        const int ii = eidx[j];
        float uv = sm.sU[ii], ov = sm.sO[ii], pv = sm.sH[ii];
        float pm = pv + (ov - pv) * uv;
        out_pmu[obase + ii] = pm;
        float a = avv[j];
        float at2 = pm + (xcar[j] - pm) * a;
        out_att[obase + ii] = at2;
        if (last) {
          out_h[(size_t)n * HH + ii] = at2;
        } else {
          float h = xnv[j] + (at2 - xnv[j]) * m2;
          sm.sH[ii] = h;
          sm.u.im.stacked[stSw[j]] = f2bf(h);
          xcar[j] = xnv[j];
        }
      }
    }
    __syncthreads();
  }
}

extern "C" void kernel_launch(void* const* d_in, const int* in_sizes, int n_in,
                              void* d_out, int out_size, void* d_ws, size_t ws_size,
                              hipStream_t stream)
{
  const float* x    = (const float*)d_in[0];
  const float* hxs  = (const float*)d_in[1];
  const float* att  = (const float*)d_in[2];
  const float* mks  = (const float*)d_in[3];
  const float* pact = (const float*)d_in[4];
  const float* Wr1  = (const float*)d_in[5];
  const float* br1  = (const float*)d_in[6];
  const float* Wr2  = (const float*)d_in[7];
  const float* br2  = (const float*)d_in[8];
  const float* Wu1  = (const float*)d_in[9];
  const float* bu1  = (const float*)d_in[10];
  const float* Wu2  = (const float*)d_in[11];
  const float* bu2  = (const float*)d_in[12];
  const float* Wo1  = (const float*)d_in[13];
  const float* bo1  = (const float*)d_in[14];
  const float* Wo2  = (const float*)d_in[15];
  const float* bo2  = (const float*)d_in[16];

  convgru_mfma<<<dim3(NB), dim3(NTHR), 0, stream>>>(
      x, hxs, att, mks, pact,
      Wr1, br1, Wr2, br2, Wu1, bu1, Wu2, bu2, Wo1, bo1, Wo2, bo2,
      (float*)d_out);
}

// Round 10
// 244.455 us; speedup vs baseline: 2.3263x; 2.3263x over previous
//
#include <hip/hip_runtime.h>
#include <math.h>

// ConvGRU scan, bf16 MFMA 16x16x32, 128 blocks x 512 threads (8 waves).
// r5 structure (proven 272us) with the epilogue FUSED into P4: the o2 wave
// owning tile (stile,mt) computes tanh in regs and directly does the GRU
// blend + attended + out stores + sH/stacked(t+1) update for its (co,s)
// elements. 4 barriers/step (was 5), sO array and P5 read-backs deleted.
// Register budget: 36 A-frags = 144 AGPRs (the proven-fitting maximum).

#define TT 64
#define NB 128
#define CC 32
#define AA 8
#define SS 49
#define HH 1568
#define KK 288      // 9 taps * 32 channels, all six convs
#define NKB 9
#define NPOS 81
#define NTHR 512

typedef short bf16x8 __attribute__((ext_vector_type(8)));
typedef short bf16x4 __attribute__((ext_vector_type(4)));
typedef float f32x4 __attribute__((ext_vector_type(4)));

struct __align__(16) SMEM {
  union {
    short staging[CC * KK];             // 9216 shorts weight scratch
    struct {
      short stacked[NPOS * CC];         // prev (or prev*r), swizzled
      short img_u[NPOS * CC];           // u1 / o1 relu output
      short img_r[NPOS * CC];           // r1 relu output
    } im;
  } u;
  short wsum[3 * 9 * CC * AA];          // bf16 class-summed inp weights [g][cls][co][ci]
  short cArr[3 * 9 * CC];               // per-step inp term + conv1 bias [g][cls][co]
  float sH[HH];
  float sU[HH];
  float bias[6 * CC];                   // bu1,bu2,br1,br2,bo1,bo2
};

__device__ __forceinline__ short f2bf(float v) {
  union { float f; unsigned u; } a; a.f = v;
  unsigned r = a.u + 0x7FFFu + ((a.u >> 16) & 1u);
  return (short)(r >> 16);
}
__device__ __forceinline__ float b2f(short h) {
  union { unsigned u; float f; } a; a.u = ((unsigned)(unsigned short)h) << 16;
  return a.f;
}
__device__ __forceinline__ float sigm(float v) { return 1.f / (1.f + __expf(-v)); }
__device__ __forceinline__ float tanhfast(float v) { return 2.f / (1.f + __expf(-2.f * v)) - 1.f; }

// image addr swizzle: 32 shorts (64B) per position. XOR short-index bits 3..4
// with (p>>1)&3 -> 8 consecutive positions hit 8 distinct 16B bank groups.
__device__ __forceinline__ int swz(int p, int ci) {
  return ((p << 5) + ci) ^ (((p >> 1) & 3) << 3);
}
__device__ __forceinline__ int clsOf(int s) {
  int y = s / 7, x = s - y * 7;
  return (y == 0 ? 0 : (y == 6 ? 6 : 3)) + (x == 0 ? 0 : (x == 6 ? 2 : 1));
}

#define MFMA(A, B, C) __builtin_amdgcn_mfma_f32_16x16x32_bf16((A), (B), (C), 0, 0, 0)

__device__ __forceinline__ f32x4 conv288(const short* img, const bf16x8 (&fA)[NKB],
                                         const int (&ad)[NKB])
{
  f32x4 a0 = {0.f, 0.f, 0.f, 0.f}, a1 = {0.f, 0.f, 0.f, 0.f};
#pragma unroll
  for (int b = 0; b < NKB; b += 2) {
    a0 = MFMA(fA[b], *(const bf16x8*)(img + ad[b]), a0);
    if (b + 1 < NKB)
      a1 = MFMA(fA[b + 1], *(const bf16x8*)(img + ad[b + 1]), a1);
  }
  return a0 + a1;
}

__global__ __launch_bounds__(NTHR, 2)
void convgru_mfma(const float* __restrict__ x, const float* __restrict__ hxs,
                  const float* __restrict__ att, const float* __restrict__ masks,
                  const float* __restrict__ pact,
                  const float* __restrict__ Wr1, const float* __restrict__ br1,
                  const float* __restrict__ Wr2, const float* __restrict__ br2,
                  const float* __restrict__ Wu1, const float* __restrict__ bu1,
                  const float* __restrict__ Wu2, const float* __restrict__ bu2,
                  const float* __restrict__ Wo1, const float* __restrict__ bo1,
                  const float* __restrict__ Wo2, const float* __restrict__ bo2,
                  float* __restrict__ out)
{
  __shared__ SMEM sm;
  const int n = blockIdx.x;
  const int tid = threadIdx.x;
  const int w = __builtin_amdgcn_readfirstlane(tid >> 6);
  const int lane = tid & 63;
  const int gate = w >> 2;            // 0=u, 1=r
  const int wq = w & 3;
  const int mt = w & 1;
  const int sbase = (wq >> 1) * 2;    // P1/P2 stile pair base
  const int stO = w >> 1;             // P3/P4 stile
  const int fg = lane >> 4;
  const int col = lane & 15;
  const int co0 = mt * 16 + fg * 4;

  // ---- bias staging
  if (tid < 6 * CC) {
    const float* bsrc[6] = {bu1, bu2, br1, br2, bo1, bo2};
    sm.bias[tid] = bsrc[tid >> 5][tid & 31];
  }

  // ---- weight transpose staging + per-wave A-frag preload (k = tap*32 + pc)
  bf16x8 fG1[NKB], fG2[NKB], fO1[NKB], fO2[NKB];
  {
    const float* wsrc[6] = {Wu1, Wr1, Wo1, Wu2, Wr2, Wo2};
    const int fco = mt * 16 + col;
#pragma unroll
    for (int cv = 0; cv < 6; ++cv) {
      __syncthreads();
      const float* wp = wsrc[cv];
      const int cin = (cv < 3) ? (AA + CC) : CC;
      const int cofs = (cv < 3) ? AA : 0;
      for (int i = tid; i < CC * KK; i += NTHR) {
        int co = i / KK, k = i - co * KK;
        int tap = k >> 5, pc = k & 31;
        sm.u.staging[(co * KK + k) ^ ((co & 7) << 3)] =
            f2bf(wp[(co * cin + cofs + pc) * 9 + tap]);
      }
      __syncthreads();
      auto loadfr = [&](bf16x8 (&dst)[NKB]) {
#pragma unroll
        for (int b = 0; b < NKB; ++b)
          dst[b] = *(const bf16x8*)&sm.u.staging[(fco * KK + b * 32 + fg * 8) ^ ((fco & 7) << 3)];
      };
      if (cv == 0) { if (gate == 0) loadfr(fG1); }
      else if (cv == 1) { if (gate == 1) loadfr(fG1); }
      else if (cv == 2) { loadfr(fO1); }
      else if (cv == 3) { if (gate == 0) loadfr(fG2); }
      else if (cv == 4) { if (gate == 1) loadfr(fG2); }
      else { loadfr(fO2); }
    }
  }
  __syncthreads();

  // ---- zero images (borders stay 0; staging 9216 covers 3*81*32=7776) + Wsum
  for (int i = tid; i < CC * KK; i += NTHR) sm.u.staging[i] = 0;
  {
    const float* w1s[3] = {Wu1, Wr1, Wo1};
    for (int e = tid; e < 3 * 9 * CC * AA; e += NTHR) {
      int g = e / 2304, rem = e - g * 2304;
      int cls = rem >> 8;
      int co = (rem >> 3) & 31, ci = e & 7;
      int yt = cls / 3, xt = cls - yt * 3;
      const float* wp = w1s[g] + (co * (AA + CC) + ci) * 9;
      float s = 0.f;
#pragma unroll
      for (int r = 0; r < 3; ++r) {
        if ((yt == 0 && r == 0) || (yt == 2 && r == 2)) continue;
#pragma unroll
        for (int c = 0; c < 3; ++c) {
          if ((xt == 0 && c == 0) || (xt == 2 && c == 2)) continue;
          s += wp[r * 3 + c];
        }
      }
      sm.wsum[e] = f2bf(s);
    }
  }

  // ---- per-lane spatial precompute (t-invariant, swizzled)
  // P1/P2: stile pair sbase..sbase+1, single mtile
  int sg[2], poutG[2], clsAG[2], inG[2][NKB]; bool vG[2];
#pragma unroll
  for (int j = 0; j < 2; ++j) {
    int s = (sbase + j) * 16 + col;
    vG[j] = (s < SS); int sc = vG[j] ? s : (SS - 1); sg[j] = sc;
    int y = sc / 7, xx = sc - y * 7;
    int p0 = y * 9 + xx;
    poutG[j] = swz(p0 + 10, co0);
    clsAG[j] = ((gate * 9 + clsOf(sc)) << 5) + co0;
#pragma unroll
    for (int b = 0; b < NKB; ++b)
      inG[j][b] = swz(p0 + (b / 3) * 9 + (b % 3), fg * 8);
  }
  // P3/P4 + fused epilogue: stile stO, single mtile
  int sOv, pout_swO, clsAO, inO[NKB], epiBase, stkBase; bool vO;
  {
    int s = stO * 16 + col;
    vO = (s < SS); int sc = vO ? s : (SS - 1); sOv = sc;
    int y = sc / 7, xx = sc - y * 7;
    int p0 = y * 9 + xx;
    pout_swO = swz(p0 + 10, co0);
    clsAO = ((2 * 9 + clsOf(sc)) << 5) + co0;
    epiBase = co0 * SS + sOv;            // +49*q walks the 4 co values
    stkBase = swz(p0 + 10, co0);         // +q walks co (q<4, no carry into swz bits)
#pragma unroll
    for (int b = 0; b < NKB; ++b)
      inO[b] = swz(p0 + (b / 3) * 9 + (b % 3), fg * 8);
  }

  float* out_pmu = out;
  float* out_att = out + (size_t)TT * NB * HH;
  float* out_h   = out + (size_t)2 * TT * NB * HH;

  __syncthreads();

  // conv2 biases to registers
  f32x4 biaG2, biaO2;
#pragma unroll
  for (int q = 0; q < 4; ++q) {
    biaG2[q] = sm.bias[(gate * 2 + 1) * 32 + co0 + q];
    biaO2[q] = sm.bias[5 * 32 + co0 + q];
  }

  // ---- carr weights PRELOADED to registers
  const int e1 = tid + NTHR;
  const bool ok1 = (e1 < 3 * 9 * CC);
  bf16x8 wR0 = *(const bf16x8*)&sm.wsum[tid << 3];
  float bR0 = sm.bias[((tid / 288) << 6) + (tid & 31)];
  bf16x8 wR1 = ok1 ? *(const bf16x8*)&sm.wsum[e1 << 3] : wR0;
  float bR1 = ok1 ? sm.bias[((e1 / 288) << 6) + (e1 & 31)] : 0.f;

  auto carr = [&](const float (&v)[8]) {
    float acc = bR0;
#pragma unroll
    for (int q = 0; q < 8; ++q) acc = fmaf(b2f(wR0[q]), v[q], acc);
    sm.cArr[tid] = f2bf(acc);
    if (ok1) {
      float a2 = bR1;
#pragma unroll
      for (int q = 0; q < 8; ++q) a2 = fmaf(b2f(wR1[q]), v[q], a2);
      sm.cArr[e1] = f2bf(a2);
    }
  };

  // ---- step-0 build: hidden + stacked (coalesced one-time pass)
  {
    const float m0 = masks[n];
    const float* x0 = x + (size_t)n * HH;
    const float* h0 = hxs + (size_t)n * HH;
    for (int i = tid; i < HH; i += NTHR) {
      float h = h0[i] * m0 + x0[i] * (1.f - m0);
      sm.sH[i] = h;
      int co = i / SS, s = i - co * SS;
      int y = s / 7, xx = s - y * 7;
      sm.u.im.stacked[swz(y * 9 + xx + 10, co)] = f2bf(h);
    }
    float v0[8];
    const float* pa0 = pact + (size_t)n * AA;
#pragma unroll
    for (int q = 0; q < 8; ++q) v0[q] = pa0[q] * m0;
    carr(v0);
  }
  // xcar: x(t) at this thread's epilogue elements
  float xcar[4];
  {
    const float* x0 = x + (size_t)n * HH;
#pragma unroll
    for (int q = 0; q < 4; ++q) xcar[q] = x0[epiBase + q * SS];
  }
  __syncthreads();

  for (int t = 0; t < TT; ++t) {
    const bool last = (t == TT - 1);
    const size_t obase = ((size_t)(t * NB) + n) * HH;

    // prefetch: att(t), x(t+1) at epilogue elements; masks/pact(t+1)
    const float* atp = att + obase;
    const int tn = last ? t : (t + 1);
    const float* xnp = x + ((size_t)(tn * NB) + n) * HH;
    float xnv[4], avv[4];
#pragma unroll
    for (int q = 0; q < 4; ++q) {
      avv[q] = atp[epiBase + q * SS];
      xnv[q] = xnp[epiBase + q * SS];
    }
    const float m2 = last ? 0.f : masks[(t + 1) * NB + n];
    float vN[8];
    const float* pap = pact + ((size_t)(tn * NB) + n) * AA;
#pragma unroll
    for (int q = 0; q < 8; ++q) vN[q] = pap[q] * m2;

    // P1: u1 / r1 (+cArr class term, relu) -> img_u / img_r
    {
      short* imgOut = gate ? sm.u.im.img_r : sm.u.im.img_u;
#pragma unroll
      for (int j = 0; j < 2; ++j) {
        f32x4 a = conv288(sm.u.im.stacked, fG1, inG[j]);
        if (vG[j]) {
          bf16x4 c4 = *(const bf16x4*)&sm.cArr[clsAG[j]];
          bf16x4 pk;
#pragma unroll
          for (int q = 0; q < 4; ++q) pk[q] = f2bf(fmaxf(a[q] + b2f(c4[q]), 0.f));
          *(bf16x4*)&imgOut[poutG[j]] = pk;
        }
      }
    }
    __syncthreads();

    // P2: u2 -> sigmoid -> sU ; r2 -> sigmoid*prev -> stacked (in place)
    if (gate == 0) {
#pragma unroll
      for (int j = 0; j < 2; ++j) {
        f32x4 a = conv288(sm.u.im.img_u, fG2, inG[j]);
        if (vG[j]) {
#pragma unroll
          for (int q = 0; q < 4; ++q)
            sm.sU[(co0 + q) * SS + sg[j]] = sigm(a[q] + biaG2[q]);
        }
      }
    } else {
#pragma unroll
      for (int j = 0; j < 2; ++j) {
        f32x4 a = conv288(sm.u.im.img_r, fG2, inG[j]);
        if (vG[j]) {
          bf16x4 pk;
#pragma unroll
          for (int q = 0; q < 4; ++q) {
            float rv = sigm(a[q] + biaG2[q]);
            pk[q] = f2bf(sm.sH[(co0 + q) * SS + sg[j]] * rv);
          }
          *(bf16x4*)&sm.u.im.stacked[poutG[j]] = pk;
        }
      }
    }
    __syncthreads();

    // P3: o1 on stacked2 (+cArr class term, relu) -> img_u, 8 jobs / 8 waves
    {
      f32x4 a = conv288(sm.u.im.stacked, fO1, inO);
      if (vO) {
        bf16x4 c4 = *(const bf16x4*)&sm.cArr[clsAO];
        bf16x4 pk;
#pragma unroll
        for (int q = 0; q < 4; ++q) pk[q] = f2bf(fmaxf(a[q] + b2f(c4[q]), 0.f));
        *(bf16x4*)&sm.u.im.img_u[pout_swO] = pk;
      }
    }
    __syncthreads();

    // P4: o2 -> tanh (in regs) -> FUSED epilogue: GRU blend, attended,
    //     out stores, sH/stacked(t+1).  Then carr(t+1).
    {
      f32x4 a = conv288(sm.u.im.img_u, fO2, inO);
      if (vO) {
#pragma unroll
        for (int q = 0; q < 4; ++q) {
          const int ii = epiBase + q * SS;
          float ov = tanhfast(a[q] + biaO2[q]);
          float uv = sm.sU[ii];
          float pv = sm.sH[ii];
          float pm = pv + (ov - pv) * uv;
          out_pmu[obase + ii] = pm;
          float at2 = pm + (xcar[q] - pm) * avv[q];
          out_att[obase + ii] = at2;
          if (last) {
            out_h[(size_t)n * HH + ii] = at2;
          } else {
            float h = xnv[q] + (at2 - xnv[q]) * m2;
            sm.sH[ii] = h;
            sm.u.im.stacked[stkBase + q] = f2bf(h);
            xcar[q] = xnv[q];
          }
        }
      }
      if (!last) carr(vN);
    }
    __syncthreads();
  }
}

extern "C" void kernel_launch(void* const* d_in, const int* in_sizes, int n_in,
                              void* d_out, int out_size, void* d_ws, size_t ws_size,
                              hipStream_t stream)
{
  const float* x    = (const float*)d_in[0];
  const float* hxs  = (const float*)d_in[1];
  const float* att  = (const float*)d_in[2];
  const float* mks  = (const float*)d_in[3];
  const float* pact = (const float*)d_in[4];
  const float* Wr1  = (const float*)d_in[5];
  const float* br1  = (const float*)d_in[6];
  const float* Wr2  = (const float*)d_in[7];
  const float* br2  = (const float*)d_in[8];
  const float* Wu1  = (const float*)d_in[9];
  const float* bu1  = (const float*)d_in[10];
  const float* Wu2  = (const float*)d_in[11];
  const float* bu2  = (const float*)d_in[12];
  const float* Wo1  = (const float*)d_in[13];
  const float* bo1  = (const float*)d_in[14];
  const float* Wo2  = (const float*)d_in[15];
  const float* bo2  = (const float*)d_in[16];

  convgru_mfma<<<dim3(NB), dim3(NTHR), 0, stream>>>(
      x, hxs, att, mks, pact,
      Wr1, br1, Wr2, br2, Wu1, bu1, Wu2, bu2, Wo1, bo1, Wo2, bo2,
      (float*)d_out);
}